// Round 1
// baseline (153.951 us; speedup 1.0000x reference)
//
#include <hip/hip_runtime.h>
#include <stdint.h>

#define LEN 512
#define NB 64
#define NCX 64
#define NCV 4
#define NCU 4

// ---------------- Threefry-2x32, 20 rounds, key = (0, 42) ----------------
__device__ __forceinline__ uint32_t rotl32(uint32_t v, int r) {
  return (v << r) | (v >> (32 - r));
}

__device__ __forceinline__ void threefry2x32_k042(uint32_t c0, uint32_t c1,
                                                  uint32_t& o0, uint32_t& o1) {
  const uint32_t ks0 = 0u, ks1 = 42u;
  const uint32_t ks2 = 0u ^ 42u ^ 0x1BD11BDAu;
  uint32_t x0 = c0 + ks0;
  uint32_t x1 = c1 + ks1;
#define TF_ROUND(R) { x0 += x1; x1 = rotl32(x1, R); x1 ^= x0; }
  // group 1: rotations {13,15,26,6}
  TF_ROUND(13) TF_ROUND(15) TF_ROUND(26) TF_ROUND(6)
  x0 += ks1; x1 += ks2 + 1u;
  // group 2: {17,29,16,24}
  TF_ROUND(17) TF_ROUND(29) TF_ROUND(16) TF_ROUND(24)
  x0 += ks2; x1 += ks0 + 2u;
  // group 3
  TF_ROUND(13) TF_ROUND(15) TF_ROUND(26) TF_ROUND(6)
  x0 += ks0; x1 += ks1 + 3u;
  // group 4
  TF_ROUND(17) TF_ROUND(29) TF_ROUND(16) TF_ROUND(24)
  x0 += ks1; x1 += ks2 + 4u;
  // group 5
  TF_ROUND(13) TF_ROUND(15) TF_ROUND(26) TF_ROUND(6)
  x0 += ks2; x1 += ks0 + 5u;
#undef TF_ROUND
  o0 = x0; o1 = x1;
}

// ---------------- Kernel 1: build permutation, ml, mask_p ----------------
// perm semantics (matches jnp.argsort(-rand) stable ascending):
//   positions [0, n_inv): invalid slots ordered by rand DESC, ties idx ASC
//   positions [n_inv, L): valid slots in original index order
__global__ __launch_bounds__(LEN) void build_perm(const void* __restrict__ mask,
                                                  int* __restrict__ src,
                                                  int* __restrict__ ml_arr,
                                                  float* __restrict__ mask_out) {
  const int b = blockIdx.x;
  const int l = threadIdx.x;
  __shared__ uint32_t key_s[LEN];

  // runtime mask-dtype detection: first element is always valid (len >= 256)
  const uint32_t w0 = ((const uint32_t*)mask)[0];
  bool valid;
  if (w0 == 1u) {                       // int32 0/1
    valid = ((const int*)mask)[b * LEN + l] != 0;
  } else if (w0 == 0x3F800000u) {       // float32 0.0/1.0
    valid = ((const float*)mask)[b * LEN + l] != 0.0f;
  } else {                              // 1-byte bool
    valid = ((const unsigned char*)mask)[b * LEN + l] != 0;
  }

  // JAX partitionable random bits for flat index i = b*L + l:
  // counter = (hi=0, lo=i); bits = out0 ^ out1
  uint32_t o0, o1;
  threefry2x32_k042(0u, (uint32_t)(b * LEN + l), o0, o1);
  const uint32_t bits = o0 ^ o1;
  // uniform [0,1): bitcast((bits>>9)|0x3F800000) - 1.0 ; monotone in the
  // uint pattern ui below, so sort on ui directly. ui >= 0x3F800000 always,
  // so 0 is a safe "valid slot" sentinel.
  const uint32_t ui = (bits >> 9) | 0x3F800000u;
  key_s[l] = valid ? 0u : ui;
  __syncthreads();

  const uint32_t me = key_s[l];
  int n_inv = 0, rank = 0;
  for (int j = 0; j < LEN; ++j) {
    const uint32_t kj = key_s[j];
    const bool inv = (kj != 0u);
    n_inv += inv;
    if (me != 0u) {
      // my rank among invalid slots: larger rand first, tie -> smaller idx
      rank += (inv && (kj > me || (kj == me && j < l))) ? 1 : 0;
    } else {
      // my rank among valid slots: original order
      rank += (!inv && j < l) ? 1 : 0;
    }
  }
  const int pos = (me != 0u) ? rank : (n_inv + rank);
  src[b * LEN + pos] = l;

  const int nv = LEN - n_inv;
  const int ml = nv < 1 ? 1 : nv;
  if (l == 0) ml_arr[b] = ml;
  // mask_p[p] = mask[src[p]] && p < ml  ->  1 exactly on [n_inv, ml)
  mask_out[b * LEN + l] = (l >= n_inv && l < ml) ? 1.0f : 0.0f;
}

// ---------------- Kernel 2/3: gather + trim for x and v ----------------
__global__ void gather_rows(const float* __restrict__ in, float* __restrict__ out,
                            const int* __restrict__ src, const int* __restrict__ ml_arr,
                            int log2C, int total) {
  const int idx = blockIdx.x * blockDim.x + threadIdx.x;
  if (idx >= total) return;
  const int p = idx & (LEN - 1);
  const int bc = idx >> 9;
  const int b = bc >> log2C;
  float val = 0.0f;
  if (p < ml_arr[b]) {
    val = in[(bc << 9) + src[b * LEN + p]];
  }
  out[idx] = val;
}

// ---------------- Kernel 4: uu[b,c,perm[i],perm[j]] ----------------
// One block handles 16 output rows; each row: coalesced 2KB load -> LDS ->
// permuted LDS gather -> coalesced float2 store. Never crosses b (2048 rows/b).
__global__ __launch_bounds__(256) void uu_perm(const float* __restrict__ in,
                                               float* __restrict__ out,
                                               const int* __restrict__ src) {
  __shared__ int s_src[LEN];
  __shared__ float s_row[LEN];
  const int tid = threadIdx.x;
  const int row0 = blockIdx.x * 16;
  const int b = row0 >> 11;  // / (NCU * LEN)

  for (int t = tid; t < LEN; t += 256) s_src[t] = src[b * LEN + t];
  __syncthreads();

  for (int r = 0; r < 16; ++r) {
    const int row = row0 + r;            // (b*NCU + c)*LEN + i
    const int i = row & (LEN - 1);
    const long inb = ((long)(row - i) + s_src[i]) * (long)LEN;
    const float2 tmp = *reinterpret_cast<const float2*>(in + inb + tid * 2);
    __syncthreads();  // prior iteration's LDS gathers complete
    *reinterpret_cast<float2*>(&s_row[tid * 2]) = tmp;
    __syncthreads();
    float2 o;
    o.x = s_row[s_src[tid * 2]];
    o.y = s_row[s_src[tid * 2 + 1]];
    *reinterpret_cast<float2*>(out + (long)row * LEN + tid * 2) = o;
  }
}

extern "C" void kernel_launch(void* const* d_in, const int* in_sizes, int n_in,
                              void* d_out, int out_size, void* d_ws, size_t ws_size,
                              hipStream_t stream) {
  const float* x  = (const float*)d_in[0];   // (64,64,512)
  const float* v  = (const float*)d_in[1];   // (64,4,512)
  const float* uu = (const float*)d_in[2];   // (64,4,512,512)
  const void*  mask = d_in[3];               // (64,1,512) bool/int/float

  float* out   = (float*)d_out;
  float* out_x = out;                        // 2,097,152
  float* out_v = out + 2097152;              // 131,072
  float* out_m = out + 2228224;              // 32,768
  float* out_u = out + 2260992;              // 67,108,864

  int* src = (int*)d_ws;                     // 64*512 ints
  int* ml  = src + NB * LEN;                 // 64 ints

  build_perm<<<NB, LEN, 0, stream>>>(mask, src, ml, out_m);

  const int total_x = NB * NCX * LEN;        // 2,097,152
  gather_rows<<<total_x / 256, 256, 0, stream>>>(x, out_x, src, ml, 6, total_x);

  const int total_v = NB * NCV * LEN;        // 131,072
  gather_rows<<<total_v / 256, 256, 0, stream>>>(v, out_v, src, ml, 2, total_v);

  uu_perm<<<(NB * NCU * LEN) / 16, 256, 0, stream>>>(uu, out_u, src);
}

// Round 2
// 152.873 us; speedup vs baseline: 1.0071x; 1.0071x over previous
//
#include <hip/hip_runtime.h>
#include <stdint.h>

#define LEN 512
#define NB 64
#define NCX 64
#define NCV 4
#define NCU 4

// ---------------- Threefry-2x32, 20 rounds, key = (0, 42) ----------------
__device__ __forceinline__ uint32_t rotl32(uint32_t v, int r) {
  return (v << r) | (v >> (32 - r));
}

__device__ __forceinline__ void threefry2x32_k042(uint32_t c0, uint32_t c1,
                                                  uint32_t& o0, uint32_t& o1) {
  const uint32_t ks0 = 0u, ks1 = 42u;
  const uint32_t ks2 = 0u ^ 42u ^ 0x1BD11BDAu;
  uint32_t x0 = c0 + ks0;
  uint32_t x1 = c1 + ks1;
#define TF_ROUND(R) { x0 += x1; x1 = rotl32(x1, R); x1 ^= x0; }
  TF_ROUND(13) TF_ROUND(15) TF_ROUND(26) TF_ROUND(6)
  x0 += ks1; x1 += ks2 + 1u;
  TF_ROUND(17) TF_ROUND(29) TF_ROUND(16) TF_ROUND(24)
  x0 += ks2; x1 += ks0 + 2u;
  TF_ROUND(13) TF_ROUND(15) TF_ROUND(26) TF_ROUND(6)
  x0 += ks0; x1 += ks1 + 3u;
  TF_ROUND(17) TF_ROUND(29) TF_ROUND(16) TF_ROUND(24)
  x0 += ks1; x1 += ks2 + 4u;
  TF_ROUND(13) TF_ROUND(15) TF_ROUND(26) TF_ROUND(6)
  x0 += ks2; x1 += ks0 + 5u;
#undef TF_ROUND
  o0 = x0; o1 = x1;
}

// ---------------- Kernel 1: build permutation, ml, mask_p ----------------
// perm semantics (matches jnp.argsort(-rand) stable ascending):
//   positions [0, n_inv): invalid slots ordered by rand DESC, ties idx ASC
//   positions [n_inv, L): valid slots in original index order
__global__ __launch_bounds__(LEN) void build_perm(const void* __restrict__ mask,
                                                  int* __restrict__ src,
                                                  int* __restrict__ ml_arr,
                                                  float* __restrict__ mask_out) {
  const int b = blockIdx.x;
  const int l = threadIdx.x;
  __shared__ uint32_t key_s[LEN];

  // runtime mask-dtype detection: first element is always valid (len >= 256)
  const uint32_t w0 = ((const uint32_t*)mask)[0];
  bool valid;
  if (w0 == 1u) {                       // int32 0/1
    valid = ((const int*)mask)[b * LEN + l] != 0;
  } else if (w0 == 0x3F800000u) {       // float32 0.0/1.0
    valid = ((const float*)mask)[b * LEN + l] != 0.0f;
  } else {                              // 1-byte bool
    valid = ((const unsigned char*)mask)[b * LEN + l] != 0;
  }

  uint32_t o0, o1;
  threefry2x32_k042(0u, (uint32_t)(b * LEN + l), o0, o1);
  const uint32_t bits = o0 ^ o1;
  const uint32_t ui = (bits >> 9) | 0x3F800000u;  // monotone in uniform value
  key_s[l] = valid ? 0u : ui;
  __syncthreads();

  const uint32_t me = key_s[l];
  int n_inv = 0, rank = 0;
  for (int j = 0; j < LEN; ++j) {
    const uint32_t kj = key_s[j];
    const bool inv = (kj != 0u);
    n_inv += inv;
    if (me != 0u) {
      rank += (inv && (kj > me || (kj == me && j < l))) ? 1 : 0;
    } else {
      rank += (!inv && j < l) ? 1 : 0;
    }
  }
  const int pos = (me != 0u) ? rank : (n_inv + rank);
  src[b * LEN + pos] = l;

  const int nv = LEN - n_inv;
  const int ml = nv < 1 ? 1 : nv;
  if (l == 0) ml_arr[b] = ml;
  mask_out[b * LEN + l] = (l >= n_inv && l < ml) ? 1.0f : 0.0f;
}

// ---------------- Kernel 2/3: gather + trim for x and v ----------------
__global__ void gather_rows(const float* __restrict__ in, float* __restrict__ out,
                            const int* __restrict__ src, const int* __restrict__ ml_arr,
                            int log2C, int total) {
  const int idx = blockIdx.x * blockDim.x + threadIdx.x;
  if (idx >= total) return;
  const int p = idx & (LEN - 1);
  const int bc = idx >> 9;
  const int b = bc >> log2C;
  float val = 0.0f;
  if (p < ml_arr[b]) {
    val = in[(bc << 9) + src[b * LEN + p]];
  }
  out[idx] = val;
}

// ---------------- Kernel 4: uu[b,c,perm[i],perm[j]] ----------------
// 32 output rows per block, staged 8 rows at a time through double-buffered
// LDS. float4 global loads/stores. One lgkmcnt-only barrier per stage so
// prefetch loads stay in flight across barriers (no vmcnt(0) drain).
__global__ __launch_bounds__(256) void uu_perm(const float* __restrict__ in,
                                               float* __restrict__ out,
                                               const int* __restrict__ src) {
  __shared__ int s_src[LEN];
  __shared__ float s_buf[2][8][LEN];
  const int tid = threadIdx.x;
  const int row0 = blockIdx.x * 32;            // all 32 rows in one (b,c) plane
  const int b = row0 >> 11;                    // / (NCU*LEN)
  const long plane_base = (long)(row0 & ~(LEN - 1)) * LEN;
  const int i0 = row0 & (LEN - 1);

  for (int t = tid; t < LEN; t += 256) s_src[t] = src[b * LEN + t];
  __syncthreads();

  const int hi = tid >> 7;                     // row parity within a pair-pass
  const int j0 = (tid & 127) * 4;              // column base (gather + store)
  // column gather sources are the same for every row: hoist to registers
  const int c0 = s_src[j0], c1 = s_src[j0 + 1], c2 = s_src[j0 + 2], c3 = s_src[j0 + 3];

  float4 r[4];
  // prologue: load stage 0
#pragma unroll
  for (int p = 0; p < 4; ++p) {
    const int sr = 2 * p + hi;
    r[p] = *reinterpret_cast<const float4*>(
        in + plane_base + (long)s_src[i0 + sr] * LEN + j0);
  }
  // write stage 0 -> buf0 (compiler inserts vmcnt waits for r[] here)
#pragma unroll
  for (int p = 0; p < 4; ++p)
    *reinterpret_cast<float4*>(&s_buf[0][2 * p + hi][j0]) = r[p];
  // prefetch stage 1
#pragma unroll
  for (int p = 0; p < 4; ++p) {
    const int sr = 8 + 2 * p + hi;
    r[p] = *reinterpret_cast<const float4*>(
        in + plane_base + (long)s_src[i0 + sr] * LEN + j0);
  }
  asm volatile("s_waitcnt lgkmcnt(0)\n\ts_barrier" ::: "memory");

#pragma unroll
  for (int s = 0; s < 4; ++s) {
    // gather stage s from buf[s&1] -> global (coalesced float4 stores)
#pragma unroll
    for (int p = 0; p < 4; ++p) {
      const int sr = 2 * p + hi;
      float4 o;
      o.x = s_buf[s & 1][sr][c0];
      o.y = s_buf[s & 1][sr][c1];
      o.z = s_buf[s & 1][sr][c2];
      o.w = s_buf[s & 1][sr][c3];
      *reinterpret_cast<float4*>(out + (long)(row0 + s * 8 + sr) * LEN + j0) = o;
    }
    if (s < 3) {
      // write stage s+1 regs into the other buffer (safe: last gathers from
      // that buffer were before the barrier ending iteration s-1)
#pragma unroll
      for (int p = 0; p < 4; ++p)
        *reinterpret_cast<float4*>(&s_buf[(s + 1) & 1][2 * p + hi][j0]) = r[p];
      if (s < 2) {
        // prefetch stage s+2; stays in flight across the barrier below
#pragma unroll
        for (int p = 0; p < 4; ++p) {
          const int sr = (s + 2) * 8 + 2 * p + hi;
          r[p] = *reinterpret_cast<const float4*>(
              in + plane_base + (long)s_src[i0 + sr] * LEN + j0);
        }
      }
      asm volatile("s_waitcnt lgkmcnt(0)\n\ts_barrier" ::: "memory");
    }
  }
}

extern "C" void kernel_launch(void* const* d_in, const int* in_sizes, int n_in,
                              void* d_out, int out_size, void* d_ws, size_t ws_size,
                              hipStream_t stream) {
  const float* x  = (const float*)d_in[0];   // (64,64,512)
  const float* v  = (const float*)d_in[1];   // (64,4,512)
  const float* uu = (const float*)d_in[2];   // (64,4,512,512)
  const void*  mask = d_in[3];               // (64,1,512)

  float* out   = (float*)d_out;
  float* out_x = out;                        // 2,097,152
  float* out_v = out + 2097152;              // 131,072
  float* out_m = out + 2228224;              // 32,768
  float* out_u = out + 2260992;              // 67,108,864

  int* src = (int*)d_ws;                     // 64*512 ints
  int* ml  = src + NB * LEN;                 // 64 ints

  build_perm<<<NB, LEN, 0, stream>>>(mask, src, ml, out_m);

  const int total_x = NB * NCX * LEN;        // 2,097,152
  gather_rows<<<total_x / 256, 256, 0, stream>>>(x, out_x, src, ml, 6, total_x);

  const int total_v = NB * NCV * LEN;        // 131,072
  gather_rows<<<total_v / 256, 256, 0, stream>>>(v, out_v, src, ml, 2, total_v);

  uu_perm<<<(NB * NCU * LEN) / 32, 256, 0, stream>>>(uu, out_u, src);
}